// Round 3
// baseline (765.339 us; speedup 1.0000x reference)
//
#include <hip/hip_runtime.h>

// Problem constants (from reference)
#define Hh 256
#define Ww 256
#define Cc 32
#define NV 16
#define NN 4
#define NL 4
#define RPB 4   // rows per block (block = 4 rows x 64 float4-groups)

// native clang vector type: accepted by __builtin_nontemporal_store
// (HIP's float4 is a struct and is rejected -- round-2 compile error)
typedef float f32x4 __attribute__((ext_vector_type(4)));

// One block = (v, group of 4 rows), handling ALL NN novel views.
// Each thread owns 4 consecutive x pixels -> 16B/lane nontemporal stores.
// Round-1 evidence: harness fill kernel (16B/lane stores) runs at 6.4 TB/s on
// this buffer; our 4B/lane scalar-store kernel ran at ~half that -> issue/MLP
// limited, not BW limited. Vectorize the dominant 537MB write stream.
__global__ __launch_bounds__(256) void warp_kernel(
    const float* __restrict__ feats,      // [NV, C, H, W]
    const int*   __restrict__ depth,      // [NV, 1, H, W]
    const float* __restrict__ novel,      // [NN, 2]
    const float* __restrict__ vpos,       // [NV, 2]
    float*       __restrict__ out)        // [NN, NV, C, H, W]
{
    // 1024 blocks, bijective XCD-chunk swizzle: 1024/8 = 128 contiguous
    // logical blocks per XCD (each XCD covers 2 v's worth of rows).
    const int bid     = blockIdx.x;
    const int logical = (bid & 7) * (NV * (Hh / RPB) / 8) + (bid >> 3);
    const int v  = logical >> 6;          // / (Hh/RPB)
    const int y4 = logical & 63;          // row-group within view
    const int tid = threadIdx.x;
    const int ry  = tid >> 6;             // 0..3 row within group (one wave/row)
    const int y   = y4 * RPB + ry;
    const int x0  = (tid & 63) * 4;       // first of 4 owned pixels

    const float vx = vpos[2 * v];
    const float vy = vpos[2 * v + 1];
    const float diop[NL] = {0.5f, 1.0f, 2.0f, 3.0f};

    const int* dv = depth + v * (Hh * Ww);

    // winner[n][i]: source offset sy*W+sx for pixel x0+i, or -1.
    int winner[NN][4];
    #pragma unroll
    for (int n = 0; n < NN; ++n) {
        const float dvx = vx - novel[2 * n];
        const float dvy = vy - novel[2 * n + 1];
        #pragma unroll
        for (int i = 0; i < 4; ++i) winner[n][i] = -1;
        #pragma unroll
        for (int l = 0; l < NL; ++l) {    // ascending: later layers overwrite
            // match reference: round((vpos - novel) * diop * F_CAM*FEAT_DIM), RNE
            const int dx = (int)rintf((dvx * diop[l]) * 128.0f);
            const int dy = (int)rintf((dvy * diop[l]) * 128.0f);
            const int sy = y - dy;
            const bool syok = (sy >= 0) & (sy < Hh);
            const int syc = min(max(sy, 0), Hh - 1);
            const int* drow = dv + syc * Ww;
            #pragma unroll
            for (int i = 0; i < 4; ++i) {
                const int sx = (x0 + i) - dx;
                const bool ok = syok & (sx >= 0) & (sx < Ww);
                const int sxc = min(max(sx, 0), Ww - 1);
                const int dval = drow[sxc];           // clamped => safe, L1-hot
                if (ok && dval == l) winner[n][i] = syc * Ww + sxc;
            }
        }
    }

    const size_t plane  = (size_t)Hh * Ww;
    const size_t rowoff = (size_t)y * Ww + x0;        // 16B-aligned
    const float* fv = feats + (size_t)v * Cc * plane;

    float* ob[NN];
    #pragma unroll
    for (int n = 0; n < NN; ++n)
        ob[n] = out + ((size_t)(n * NV + v) * Cc) * plane + rowoff;

    #pragma unroll 2
    for (int c = 0; c < Cc; ++c) {
        const float* fc = fv + (size_t)c * plane;
        #pragma unroll
        for (int n = 0; n < NN; ++n) {
            f32x4 val;
            val.x = winner[n][0] >= 0 ? fc[winner[n][0]] : 0.0f;
            val.y = winner[n][1] >= 0 ? fc[winner[n][1]] : 0.0f;
            val.z = winner[n][2] >= 0 ? fc[winner[n][2]] : 0.0f;
            val.w = winner[n][3] >= 0 ? fc[winner[n][3]] : 0.0f;
            // write-once stream: nontemporal 16B store, keep L2 for feats
            __builtin_nontemporal_store(val,
                (f32x4*)(ob[n] + (size_t)c * plane));
        }
    }
}

extern "C" void kernel_launch(void* const* d_in, const int* in_sizes, int n_in,
                              void* d_out, int out_size, void* d_ws, size_t ws_size,
                              hipStream_t stream) {
    const float* feats = (const float*)d_in[0];
    const int*   depth = (const int*)d_in[1];
    const float* novel = (const float*)d_in[2];
    const float* vpos  = (const float*)d_in[3];
    float* out = (float*)d_out;

    dim3 grid(NV * (Hh / RPB));  // 1024 blocks: (v, 4-row group)
    dim3 block(256);             // 4 rows x 64 float4-groups
    warp_kernel<<<grid, block, 0, stream>>>(feats, depth, novel, vpos, out);
}